// Round 5
// baseline (292.307 us; speedup 1.0000x reference)
//
#include <hip/hip_runtime.h>

// R5: (a) flash: static-max softmax (exp2-domain, log2e folded into k and rel
// tables, C=16 shift), v_perm bf16 pack, register-prefetch of next K/V tile.
// (b) GEMMs upgraded 64x64 -> 128x128 tile (m93-style, 4x4 acc/wave, BK=64).

typedef unsigned short u16;
typedef __attribute__((ext_vector_type(8))) __bf16 bf16x8;
typedef __attribute__((ext_vector_type(4))) float f32x4;

#define LOG2E 1.4426950408889634f

__device__ __forceinline__ float b2f(u16 u) {
    unsigned int i = ((unsigned int)u) << 16;
    float f; __builtin_memcpy(&f, &i, 4); return f;
}
__device__ __forceinline__ u16 f2b(float f) {
    unsigned int x; __builtin_memcpy(&x, &f, 4);
    x += 0x7fffu + ((x >> 16) & 1u);   // RTNE
    return (u16)(x >> 16);
}

#define LDT 72   // padded LDS row stride (bf16): 144B rows, 16B-aligned

// ---------------------------------------------------------------------------
// dtype detect (1 = fp32 storage) + convert-to-bf16 (optionally scaled)
// ---------------------------------------------------------------------------
__global__ void detect_dtype(const u16* __restrict__ x, int* __restrict__ flag)
{
    if (threadIdx.x == 0 && blockIdx.x == 0) {
        float mx = 0.f;
        for (int i = 0; i < 128; i++) {
            float v = fabsf(b2f(x[i]));
            if (!(v <= 1e30f)) v = 1e30f;
            mx = fmaxf(mx, v);
        }
        *flag = (mx > 1e4f) ? 1 : 0;
    }
}

__global__ __launch_bounds__(256) void convert_in(
    const void* __restrict__ src, u16* __restrict__ dst, int n, float scale,
    const int* __restrict__ flag)
{
    const int fl = *flag;
    for (int i = blockIdx.x * 256 + threadIdx.x; i < n; i += gridDim.x * 256) {
        float v = fl ? ((const float*)src)[i] : b2f(((const u16*)src)[i]);
        dst[i] = f2b(v * scale);
    }
}

// ---------------------------------------------------------------------------
// 128x128-tile GEMM (TN): C[m][n] = sum_k A[m][k]*Bw[n][k] + bias[n].
// EPI=0: proj (dual-dtype store to Cout per flag)
// EPI=1: qkv  (rope + k*0.125*log2e + scatter to qkvT; V transposed [d][l])
// ---------------------------------------------------------------------------
template <int EPI>
__global__ __launch_bounds__(256) void gemm128(
    const u16* __restrict__ A, const u16* __restrict__ Bw,
    const u16* __restrict__ bias, void* __restrict__ Cout,
    const int* __restrict__ flag, u16* __restrict__ qkvT, int N, int K)
{
    __shared__ u16 lA[128 * LDT];
    __shared__ u16 lB[128 * LDT];
    const int tid = threadIdx.x;
    const int m0 = blockIdx.x * 128, n0 = blockIdx.y * 128;
    const int wave = tid >> 6, lane = tid & 63;
    const int wm = (wave & 1) * 64, wn = (wave >> 1) * 64;
    const int lm = lane & 15, lq = lane >> 4;
    f32x4 acc[4][4] = {};
    for (int k0 = 0; k0 < K; k0 += 64) {
        if (k0) __syncthreads();
        #pragma unroll
        for (int s = tid; s < 1024; s += 256) {
            const int row = s >> 3, kg = (s & 7) * 8;
            *(uint4*)&lA[row * LDT + kg] = *(const uint4*)(A + (size_t)(m0 + row) * K + k0 + kg);
            *(uint4*)&lB[row * LDT + kg] = *(const uint4*)(Bw + (size_t)(n0 + row) * K + k0 + kg);
        }
        __syncthreads();
        #pragma unroll
        for (int ks = 0; ks < 64; ks += 32) {
            bf16x8 af[4], bfr[4];
            #pragma unroll
            for (int i = 0; i < 4; i++) af[i]  = *(const bf16x8*)&lA[(wm + i * 16 + lm) * LDT + ks + lq * 8];
            #pragma unroll
            for (int j = 0; j < 4; j++) bfr[j] = *(const bf16x8*)&lB[(wn + j * 16 + lm) * LDT + ks + lq * 8];
            #pragma unroll
            for (int i = 0; i < 4; i++)
                #pragma unroll
                for (int j = 0; j < 4; j++)
                    acc[i][j] = __builtin_amdgcn_mfma_f32_16x16x32_bf16(af[i], bfr[j], acc[i][j], 0, 0, 0);
        }
    }
    const size_t HL = (size_t)96 * 1024 * 64;
    const int which = n0 / 768;        // 768 % 128 == 0 -> block-uniform
    #pragma unroll
    for (int i = 0; i < 4; i++)
        #pragma unroll
        for (int j = 0; j < 4; j++)
            #pragma unroll
            for (int r = 0; r < 4; r++) {
                const int m = m0 + wm + i * 16 + lq * 4 + r;
                const int n = n0 + wn + j * 16 + lm;
                float v = acc[i][j][r] + b2f(bias[n]);
                if (EPI == 0) {
                    if (*flag) ((float*)Cout)[(size_t)m * 768 + n] = v;
                    else       ((u16*)Cout)[(size_t)m * 768 + n] = f2b(v);
                } else {
                    const float p = __shfl_xor(v, 1);          // rope pair partner
                    const int l = m & 1023, bb = m >> 10;
                    const int nh = (n >> 6) % 12, d = n & 63;
                    float o = v;
                    if (which < 2) {
                        const int pi = d >> 1, jj = pi & 15;
                        const float coord = (pi < 16) ? (float)(l & 31) : (float)(l >> 5);
                        const float ang = coord * __expf(-(float)jj * 0.5756462732485115f);
                        float sn, cs; __sincosf(ang, &sn, &cs);
                        o = v * cs + ((d & 1) ? p * sn : -(p * sn));
                        if (which == 1) o *= 0.125f * LOG2E;   // fold 1/sqrt(hd)*log2e into k
                    }
                    const size_t bnl = (size_t)(bb * 12 + nh);
                    size_t dst;
                    if (which == 2) dst = 2 * HL + bnl * 65536 + (size_t)d * 1024 + l;   // V^T
                    else            dst = (size_t)which * HL + (bnl * 1024 + l) * 64 + d;
                    qkvT[dst] = f2b(o);
                }
            }
}

// ---------------------------------------------------------------------------
// K2: MFMA flash attention, static-max softmax in exp2 domain.
// p = 2^(q.k' + Th + Tw - 16) with log2e pre-folded into k' and rel tables.
// Register-prefetch of next K/V tile overlaps global latency with compute.
// ---------------------------------------------------------------------------
__global__ __launch_bounds__(256) void flash_attn_mfma(
    const u16* __restrict__ qkvT, const u16* __restrict__ relH,
    const u16* __restrict__ relW, u16* __restrict__ outb)
{
    __shared__ char smem[46080];
    u16 (*ks2)[LDT] = (u16(*)[LDT])smem;                 // K tile [k][d]
    u16 (*vsT)[LDT] = (u16(*)[LDT])(smem + 9216);        // V^T tile [d][k]
    u16 (*rel)[LDT] = vsT;                               // alias: rel staging
    u16 (*qs)[LDT]  = (u16(*)[LDT])(smem + 18432);       // Q tile [q][d]
    u16 (*pT)[LDT]  = qs;                                // alias: P [q][k]
    u16 (*Th)[LDT]  = (u16(*)[LDT])(smem + 27648);       // Th[q][r]
    u16 (*Tw)[LDT]  = (u16(*)[LDT])(smem + 36864);       // Tw[q][r]

    const int tid = threadIdx.x;
    const int bn = blockIdx.x, q0 = blockIdx.y * 64;
    const size_t HL = (size_t)96 * 1024 * 64;
    const u16* qg  = qkvT + (size_t)bn * 65536 + (size_t)q0 * 64;
    const u16* kgb = qkvT + HL + (size_t)bn * 65536;
    const u16* vTg = qkvT + 2 * HL + (size_t)bn * 65536;   // [d][1024]

    for (int g = tid; g < 1024; g += 256) {
        int r = g >> 4, c = (g & 15) * 4;
        *(ushort4*)&qs[r][c] = ((const ushort4*)qg)[g];
    }
    for (int g = tid; g < 1008; g += 256) {               // relH: 63x64 (pre-scaled by log2e)
        int r = g >> 4, c = (g & 15) * 4;
        *(ushort4*)&rel[r][c] = *(const ushort4*)(relH + g * 4);
    }
    if (tid < 16) { ushort4 z = {0, 0, 0, 0}; *(ushort4*)&rel[63][tid * 4] = z; }
    __syncthreads();

    const int w = tid >> 6, lane = tid & 63;
    const int lm = lane & 15, lq = lane >> 4;

    const bf16x8 bq0 = *(const bf16x8*)&qs[w * 16 + lm][lq * 8];
    const bf16x8 bq1 = *(const bf16x8*)&qs[w * 16 + lm][32 + lq * 8];

    {   // Th = Q . relH^T
        f32x4 tacc[4] = {};
        #pragma unroll
        for (int nb = 0; nb < 4; nb++) {
            bf16x8 r0 = *(const bf16x8*)&rel[nb * 16 + lm][lq * 8];
            bf16x8 r1 = *(const bf16x8*)&rel[nb * 16 + lm][32 + lq * 8];
            tacc[nb] = __builtin_amdgcn_mfma_f32_16x16x32_bf16(bq0, r0, tacc[nb], 0, 0, 0);
            tacc[nb] = __builtin_amdgcn_mfma_f32_16x16x32_bf16(bq1, r1, tacc[nb], 0, 0, 0);
        }
        #pragma unroll
        for (int nb = 0; nb < 4; nb++)
            #pragma unroll
            for (int rr = 0; rr < 4; rr++)
                Th[w * 16 + lq * 4 + rr][nb * 16 + lm] = f2b(tacc[nb][rr]);
    }
    __syncthreads();
    for (int g = tid; g < 1008; g += 256) {               // relW
        int r = g >> 4, c = (g & 15) * 4;
        *(ushort4*)&rel[r][c] = *(const ushort4*)(relW + g * 4);
    }
    if (tid < 16) { ushort4 z = {0, 0, 0, 0}; *(ushort4*)&rel[63][tid * 4] = z; }
    __syncthreads();
    {   // Tw = Q . relW^T
        f32x4 tacc[4] = {};
        #pragma unroll
        for (int nb = 0; nb < 4; nb++) {
            bf16x8 r0 = *(const bf16x8*)&rel[nb * 16 + lm][lq * 8];
            bf16x8 r1 = *(const bf16x8*)&rel[nb * 16 + lm][32 + lq * 8];
            tacc[nb] = __builtin_amdgcn_mfma_f32_16x16x32_bf16(bq0, r0, tacc[nb], 0, 0, 0);
            tacc[nb] = __builtin_amdgcn_mfma_f32_16x16x32_bf16(bq1, r1, tacc[nb], 0, 0, 0);
        }
        #pragma unroll
        for (int nb = 0; nb < 4; nb++)
            #pragma unroll
            for (int rr = 0; rr < 4; rr++)
                Tw[w * 16 + lq * 4 + rr][nb * 16 + lm] = f2b(tacc[nb][rr]);
    }
    // hoisted w-bias (minus C=16 static-max shift)
    const int qw = (w & 1) * 16 + lm;
    float rwc[8];
    #pragma unroll
    for (int mb2 = 0; mb2 < 2; mb2++)
        #pragma unroll
        for (int rr = 0; rr < 4; rr++) {
            const int kw = mb2 * 16 + lq * 4 + rr;
            rwc[mb2 * 4 + rr] = b2f(Tw[w * 16 + lm][qw - kw + 31]) - 16.0f;
        }
    const int qh = (q0 >> 5) + (w >= 2 ? 1 : 0);

    // staging geometry + prefetch of tile 0
    const int sr = tid >> 4, scc = (tid & 15) * 4;
    ushort4 kr[4], vr[4];
    #pragma unroll
    for (int it = 0; it < 4; it++) {
        kr[it] = *(const ushort4*)(kgb + (sr + 16 * it) * 64 + scc);
        vr[it] = *(const ushort4*)(vTg + (size_t)(sr + 16 * it) * 1024 + scc);
    }

    float l_acc = 0.f;
    f32x4 oacc[4] = {};

    #pragma unroll 1
    for (int kt = 0; kt < 16; kt++) {
        __syncthreads();                                   // prior readers done
        #pragma unroll
        for (int it = 0; it < 4; it++) {
            *(ushort4*)&ks2[sr + 16 * it][scc] = kr[it];
            *(ushort4*)&vsT[sr + 16 * it][scc] = vr[it];
        }
        if (kt < 15) {                                     // prefetch next tile
            #pragma unroll
            for (int it = 0; it < 4; it++) {
                kr[it] = *(const ushort4*)(kgb + (kt + 1) * 4096 + (sr + 16 * it) * 64 + scc);
                vr[it] = *(const ushort4*)(vTg + (size_t)(sr + 16 * it) * 1024 + (kt + 1) * 64 + scc);
            }
        }
        __syncthreads();
        // S^T[k][q] = K . Q^T
        f32x4 sacc[4];
        #pragma unroll
        for (int mb = 0; mb < 4; mb++) {
            bf16x8 ka0 = *(const bf16x8*)&ks2[mb * 16 + lm][lq * 8];
            bf16x8 ka1 = *(const bf16x8*)&ks2[mb * 16 + lm][32 + lq * 8];
            f32x4 s = {};
            s = __builtin_amdgcn_mfma_f32_16x16x32_bf16(ka0, bq0, s, 0, 0, 0);
            s = __builtin_amdgcn_mfma_f32_16x16x32_bf16(ka1, bq1, s, 0, 0, 0);
            sacc[mb] = s;
        }
        const float rh0 = b2f(Th[w * 16 + lm][qh - 2 * kt + 31]);
        const float rh1 = b2f(Th[w * 16 + lm][qh - 2 * kt + 30]);
        // p = 2^(s + rh + rw - 16); accumulate l in-lane; pack via v_perm
        #pragma unroll
        for (int mb = 0; mb < 4; mb++) {
            const float rhv = (mb >= 2) ? rh1 : rh0;
            unsigned pk[2];
            #pragma unroll
            for (int h = 0; h < 2; h++) {
                float p0 = exp2f(sacc[mb][2 * h]     + rhv + rwc[(mb & 1) * 4 + 2 * h]);
                float p1 = exp2f(sacc[mb][2 * h + 1] + rhv + rwc[(mb & 1) * 4 + 2 * h + 1]);
                l_acc += p0; l_acc += p1;
                unsigned u0, u1;
                __builtin_memcpy(&u0, &p0, 4); __builtin_memcpy(&u1, &p1, 4);
                pk[h] = __builtin_amdgcn_perm(u1 + 0x8000u, u0 + 0x8000u, 0x07060302u);
            }
            uint2 u = {pk[0], pk[1]};
            *(uint2*)&pT[w * 16 + lm][mb * 16 + lq * 4] = u;   // wave-private rows
        }
        // O += P . V
        const bf16x8 pa0 = *(const bf16x8*)&pT[w * 16 + lm][lq * 8];
        const bf16x8 pa1 = *(const bf16x8*)&pT[w * 16 + lm][32 + lq * 8];
        #pragma unroll
        for (int nb = 0; nb < 4; nb++) {
            bf16x8 vb0 = *(const bf16x8*)&vsT[nb * 16 + lm][lq * 8];
            bf16x8 vb1 = *(const bf16x8*)&vsT[nb * 16 + lm][32 + lq * 8];
            oacc[nb] = __builtin_amdgcn_mfma_f32_16x16x32_bf16(pa0, vb0, oacc[nb], 0, 0, 0);
            oacc[nb] = __builtin_amdgcn_mfma_f32_16x16x32_bf16(pa1, vb1, oacc[nb], 0, 0, 0);
        }
    }
    l_acc += __shfl_xor(l_acc, 16);
    l_acc += __shfl_xor(l_acc, 32);
    const float rinv = 1.f / l_acc;
    float rv[4];
    #pragma unroll
    for (int rr = 0; rr < 4; rr++) rv[rr] = __shfl(rinv, lq * 4 + rr);
    const int bb = bn / 12, nh = bn % 12;
    #pragma unroll
    for (int nb = 0; nb < 4; nb++)
        #pragma unroll
        for (int rr = 0; rr < 4; rr++) {
            const int qrow = q0 + w * 16 + lq * 4 + rr;
            const int d = nb * 16 + lm;
            outb[((size_t)(bb * 1024 + qrow)) * 768 + nh * 64 + d] = f2b(oacc[nb][rr] * rv[rr]);
        }
}

// ---------------------------------------------------------------------------
extern "C" void kernel_launch(void* const* d_in, const int* in_sizes, int n_in,
                              void* d_out, int out_size, void* d_ws, size_t ws_size,
                              hipStream_t stream)
{
    u16* ws16  = (u16*)d_ws;
    u16* qkvT  = ws16;
    u16* xb    = ws16 + (size_t)18874368;
    u16* attn  = xb;                       // x dead after K1
    const size_t S = 25165824;
    u16* qkvw_b = ws16 + S;
    u16* projw_b = qkvw_b + 1769472;
    u16* qkvb_b = projw_b + 589824;
    u16* projb_b = qkvb_b + 2304;
    u16* relh_b = projb_b + 768;
    u16* relw_b = relh_b + 4032;
    int* flag = (int*)(ws16 + S + 2370432);

    detect_dtype<<<1, 64, 0, stream>>>((const u16*)d_in[0], flag);
    convert_in<<<6144, 256, 0, stream>>>(d_in[0], xb,      6291456, 1.0f,  flag);
    convert_in<<<1728, 256, 0, stream>>>(d_in[1], qkvw_b,  1769472, 1.0f,  flag);
    convert_in<<<9,    256, 0, stream>>>(d_in[2], qkvb_b,  2304,    1.0f,  flag);
    convert_in<<<576,  256, 0, stream>>>(d_in[3], projw_b, 589824,  1.0f,  flag);
    convert_in<<<3,    256, 0, stream>>>(d_in[4], projb_b, 768,     1.0f,  flag);
    convert_in<<<16,   256, 0, stream>>>(d_in[5], relh_b,  4032,    LOG2E, flag);
    convert_in<<<16,   256, 0, stream>>>(d_in[6], relw_b,  4032,    LOG2E, flag);

    gemm128<1><<<dim3(64, 18), 256, 0, stream>>>(xb, qkvw_b, qkvb_b, nullptr, flag, qkvT, 2304, 768);
    flash_attn_mfma<<<dim3(96, 16), 256, 0, stream>>>(qkvT, relh_b, relw_b, attn);
    gemm128<0><<<dim3(64, 6), 256, 0, stream>>>(attn, projw_b, projb_b, d_out, flag, nullptr, 768, 768);
}

// Round 6
// 284.567 us; speedup vs baseline: 1.0272x; 1.0272x over previous
//
#include <hip/hip_runtime.h>

// R6: m97-style staging. Both GEMMs and flash K/V now use
// __builtin_amdgcn_global_load_lds width=16 (async DMA direct to LDS,
// unpadded tiles, wave-uniform dest + lane*16). R5 profile: qkv gemm 117us
// with ALL pipes idle (MfmaUtil 9.5, VALU 10.7, HBM 7.5%) = exposed staging
// latency, the pre-m97 plateau. Epilogues/softmax math unchanged.

typedef unsigned short u16;
typedef __attribute__((ext_vector_type(8))) __bf16 bf16x8;
typedef __attribute__((ext_vector_type(4))) float f32x4;
typedef __attribute__((address_space(1))) const unsigned int gu32;
typedef __attribute__((address_space(3))) unsigned int lu32;

#define LOG2E 1.4426950408889634f

__device__ __forceinline__ float b2f(u16 u) {
    unsigned int i = ((unsigned int)u) << 16;
    float f; __builtin_memcpy(&f, &i, 4); return f;
}
__device__ __forceinline__ u16 f2b(float f) {
    unsigned int x; __builtin_memcpy(&x, &f, 4);
    x += 0x7fffu + ((x >> 16) & 1u);   // RTNE
    return (u16)(x >> 16);
}

#define LDT 72   // padded stride for LDS tiles still read with dynamic cols

// ---------------------------------------------------------------------------
__global__ void detect_dtype(const u16* __restrict__ x, int* __restrict__ flag)
{
    if (threadIdx.x == 0 && blockIdx.x == 0) {
        float mx = 0.f;
        for (int i = 0; i < 128; i++) {
            float v = fabsf(b2f(x[i]));
            if (!(v <= 1e30f)) v = 1e30f;
            mx = fmaxf(mx, v);
        }
        *flag = (mx > 1e4f) ? 1 : 0;
    }
}

__global__ __launch_bounds__(256) void convert_in(
    const void* __restrict__ src, u16* __restrict__ dst, int n, float scale,
    const int* __restrict__ flag)
{
    const int fl = *flag;
    for (int i = blockIdx.x * 256 + threadIdx.x; i < n; i += gridDim.x * 256) {
        float v = fl ? ((const float*)src)[i] : b2f(((const u16*)src)[i]);
        dst[i] = f2b(v * scale);
    }
}

// ---------------------------------------------------------------------------
// 128x128 GEMM (TN), BK=64, global_load_lds staging (unpadded LDS, m97-style).
// EPI=0: proj (dual-dtype store). EPI=1: qkv (rope + k-scale + scatter).
// ---------------------------------------------------------------------------
template <int EPI>
__global__ __launch_bounds__(256) void gemm128(
    const u16* __restrict__ A, const u16* __restrict__ Bw,
    const u16* __restrict__ bias, void* __restrict__ Cout,
    const int* __restrict__ flag, u16* __restrict__ qkvT, int N, int K)
{
    __shared__ __align__(16) u16 lA[128 * 64];
    __shared__ __align__(16) u16 lB[128 * 64];
    const int tid = threadIdx.x;
    const int m0 = blockIdx.x * 128, n0 = blockIdx.y * 128;
    const int wave = tid >> 6, lane = tid & 63;
    const int wm = (wave & 1) * 64, wn = (wave >> 1) * 64;
    const int lm = lane & 15, lq = lane >> 4;
    // staging: 16 chunks of 8 rows each; wave w owns chunks 4w..4w+3.
    // lane i -> row c*8 + (i>>3), col (i&7)*8; LDS dest = base(c) + lane*16.
    const int srow = lane >> 3, scol = (lane & 7) * 8;
    f32x4 acc[4][4] = {};
    for (int k0 = 0; k0 < K; k0 += 64) {
        if (k0) __syncthreads();
        #pragma unroll
        for (int c4 = 0; c4 < 4; c4++) {
            const int c = wave * 4 + c4;
            const int row = c * 8 + srow;
            __builtin_amdgcn_global_load_lds(
                (gu32*)(A + (size_t)(m0 + row) * K + k0 + scol),
                (lu32*)&lA[c * 512], 16, 0, 0);
            __builtin_amdgcn_global_load_lds(
                (gu32*)(Bw + (size_t)(n0 + row) * K + k0 + scol),
                (lu32*)&lB[c * 512], 16, 0, 0);
        }
        __syncthreads();
        #pragma unroll
        for (int ks = 0; ks < 64; ks += 32) {
            bf16x8 af[4], bfr[4];
            #pragma unroll
            for (int i = 0; i < 4; i++) af[i]  = *(const bf16x8*)&lA[(wm + i * 16 + lm) * 64 + ks + lq * 8];
            #pragma unroll
            for (int j = 0; j < 4; j++) bfr[j] = *(const bf16x8*)&lB[(wn + j * 16 + lm) * 64 + ks + lq * 8];
            #pragma unroll
            for (int i = 0; i < 4; i++)
                #pragma unroll
                for (int j = 0; j < 4; j++)
                    acc[i][j] = __builtin_amdgcn_mfma_f32_16x16x32_bf16(af[i], bfr[j], acc[i][j], 0, 0, 0);
        }
    }
    const size_t HL = (size_t)96 * 1024 * 64;
    const int which = n0 / 768;
    #pragma unroll
    for (int i = 0; i < 4; i++)
        #pragma unroll
        for (int j = 0; j < 4; j++)
            #pragma unroll
            for (int r = 0; r < 4; r++) {
                const int m = m0 + wm + i * 16 + lq * 4 + r;
                const int n = n0 + wn + j * 16 + lm;
                float v = acc[i][j][r] + b2f(bias[n]);
                if (EPI == 0) {
                    if (*flag) ((float*)Cout)[(size_t)m * 768 + n] = v;
                    else       ((u16*)Cout)[(size_t)m * 768 + n] = f2b(v);
                } else {
                    const float p = __shfl_xor(v, 1);
                    const int l = m & 1023, bb = m >> 10;
                    const int nh = (n >> 6) % 12, d = n & 63;
                    float o = v;
                    if (which < 2) {
                        const int pi = d >> 1, jj = pi & 15;
                        const float coord = (pi < 16) ? (float)(l & 31) : (float)(l >> 5);
                        const float ang = coord * __expf(-(float)jj * 0.5756462732485115f);
                        float sn, cs; __sincosf(ang, &sn, &cs);
                        o = v * cs + ((d & 1) ? p * sn : -(p * sn));
                        if (which == 1) o *= 0.125f * LOG2E;
                    }
                    const size_t bnl = (size_t)(bb * 12 + nh);
                    size_t dst;
                    if (which == 2) dst = 2 * HL + bnl * 65536 + (size_t)d * 1024 + l;   // V^T
                    else            dst = (size_t)which * HL + (bnl * 1024 + l) * 64 + d;
                    qkvT[dst] = f2b(o);
                }
            }
}

// ---------------------------------------------------------------------------
// K2: MFMA flash attention, static-max exp2 softmax, DMA-staged K/V.
// ks2/vsT unpadded [64][64] (global_load_lds); qs/pT/Th/Tw padded LDT.
// ---------------------------------------------------------------------------
__global__ __launch_bounds__(256) void flash_attn_mfma(
    const u16* __restrict__ qkvT, const u16* __restrict__ relH,
    const u16* __restrict__ relW, u16* __restrict__ outb)
{
    __shared__ __align__(16) u16 ks2[64 * 64];     // K tile [k][d]
    __shared__ __align__(16) u16 vsT[64 * 64];     // V^T tile [d][k]; aliased as rel staging
    __shared__ __align__(16) u16 qs[64 * LDT];     // Q tile [q][d]; aliased as P [q][k]
    __shared__ __align__(16) u16 Th[64 * LDT];
    __shared__ __align__(16) u16 Tw[64 * LDT];
    u16* rel = vsT;
    u16* pT  = qs;

    const int tid = threadIdx.x;
    const int bn = blockIdx.x, q0 = blockIdx.y * 64;
    const size_t HL = (size_t)96 * 1024 * 64;
    const u16* qg  = qkvT + (size_t)bn * 65536 + (size_t)q0 * 64;
    const u16* kgb = qkvT + HL + (size_t)bn * 65536;
    const u16* vTg = qkvT + 2 * HL + (size_t)bn * 65536;   // [d][1024]

    for (int g = tid; g < 1024; g += 256) {
        int r = g >> 4, c = (g & 15) * 4;
        *(ushort4*)&qs[r * LDT + c] = ((const ushort4*)qg)[g];
    }
    for (int g = tid; g < 1008; g += 256) {               // relH: 63x64 (pre-scaled log2e)
        int r = g >> 4, c = (g & 15) * 4;
        *(ushort4*)&rel[r * 64 + c] = *(const ushort4*)(relH + g * 4);
    }
    if (tid < 16) { ushort4 z = {0, 0, 0, 0}; *(ushort4*)&rel[63 * 64 + tid * 4] = z; }
    __syncthreads();

    const int w = tid >> 6, lane = tid & 63;
    const int lm = lane & 15, lq = lane >> 4;

    const bf16x8 bq0 = *(const bf16x8*)&qs[(w * 16 + lm) * LDT + lq * 8];
    const bf16x8 bq1 = *(const bf16x8*)&qs[(w * 16 + lm) * LDT + 32 + lq * 8];

    {   // Th = Q . relH^T
        f32x4 tacc[4] = {};
        #pragma unroll
        for (int nb = 0; nb < 4; nb++) {
            bf16x8 r0 = *(const bf16x8*)&rel[(nb * 16 + lm) * 64 + lq * 8];
            bf16x8 r1 = *(const bf16x8*)&rel[(nb * 16 + lm) * 64 + 32 + lq * 8];
            tacc[nb] = __builtin_amdgcn_mfma_f32_16x16x32_bf16(bq0, r0, tacc[nb], 0, 0, 0);
            tacc[nb] = __builtin_amdgcn_mfma_f32_16x16x32_bf16(bq1, r1, tacc[nb], 0, 0, 0);
        }
        #pragma unroll
        for (int nb = 0; nb < 4; nb++)
            #pragma unroll
            for (int rr = 0; rr < 4; rr++)
                Th[(w * 16 + lq * 4 + rr) * LDT + nb * 16 + lm] = f2b(tacc[nb][rr]);
    }
    __syncthreads();
    for (int g = tid; g < 1008; g += 256) {               // relW
        int r = g >> 4, c = (g & 15) * 4;
        *(ushort4*)&rel[r * 64 + c] = *(const ushort4*)(relW + g * 4);
    }
    if (tid < 16) { ushort4 z = {0, 0, 0, 0}; *(ushort4*)&rel[63 * 64 + tid * 4] = z; }
    __syncthreads();
    {   // Tw = Q . relW^T
        f32x4 tacc[4] = {};
        #pragma unroll
        for (int nb = 0; nb < 4; nb++) {
            bf16x8 r0 = *(const bf16x8*)&rel[(nb * 16 + lm) * 64 + lq * 8];
            bf16x8 r1 = *(const bf16x8*)&rel[(nb * 16 + lm) * 64 + 32 + lq * 8];
            tacc[nb] = __builtin_amdgcn_mfma_f32_16x16x32_bf16(bq0, r0, tacc[nb], 0, 0, 0);
            tacc[nb] = __builtin_amdgcn_mfma_f32_16x16x32_bf16(bq1, r1, tacc[nb], 0, 0, 0);
        }
        #pragma unroll
        for (int nb = 0; nb < 4; nb++)
            #pragma unroll
            for (int rr = 0; rr < 4; rr++)
                Tw[(w * 16 + lq * 4 + rr) * LDT + nb * 16 + lm] = f2b(tacc[nb][rr]);
    }
    const int qw = (w & 1) * 16 + lm;
    float rwc[8];
    #pragma unroll
    for (int mb2 = 0; mb2 < 2; mb2++)
        #pragma unroll
        for (int rr = 0; rr < 4; rr++) {
            const int kw = mb2 * 16 + lq * 4 + rr;
            rwc[mb2 * 4 + rr] = b2f(Tw[(w * 16 + lm) * LDT + qw - kw + 31]) - 16.0f;
        }
    const int qh = (q0 >> 5) + (w >= 2 ? 1 : 0);

    const int srow = lane >> 3, scol = (lane & 7) * 8;   // DMA geometry
    float l_acc = 0.f;
    f32x4 oacc[4] = {};

    #pragma unroll 1
    for (int kt = 0; kt < 16; kt++) {
        __syncthreads();                                   // prior tile's readers done
        const u16* kp = kgb + (size_t)kt * 4096;
        #pragma unroll
        for (int c4 = 0; c4 < 2; c4++) {
            const int c = w * 2 + c4;
            const int row = c * 8 + srow;
            __builtin_amdgcn_global_load_lds(
                (gu32*)(kp + row * 64 + scol), (lu32*)&ks2[c * 512], 16, 0, 0);
            __builtin_amdgcn_global_load_lds(
                (gu32*)(vTg + (size_t)row * 1024 + kt * 64 + scol), (lu32*)&vsT[c * 512], 16, 0, 0);
        }
        __syncthreads();                                   // DMA complete (vmcnt drain)
        f32x4 sacc[4];
        #pragma unroll
        for (int mb = 0; mb < 4; mb++) {
            bf16x8 ka0 = *(const bf16x8*)&ks2[(mb * 16 + lm) * 64 + lq * 8];
            bf16x8 ka1 = *(const bf16x8*)&ks2[(mb * 16 + lm) * 64 + 32 + lq * 8];
            f32x4 s = {};
            s = __builtin_amdgcn_mfma_f32_16x16x32_bf16(ka0, bq0, s, 0, 0, 0);
            s = __builtin_amdgcn_mfma_f32_16x16x32_bf16(ka1, bq1, s, 0, 0, 0);
            sacc[mb] = s;
        }
        const float rh0 = b2f(Th[(w * 16 + lm) * LDT + qh - 2 * kt + 31]);
        const float rh1 = b2f(Th[(w * 16 + lm) * LDT + qh - 2 * kt + 30]);
        #pragma unroll
        for (int mb = 0; mb < 4; mb++) {
            const float rhv = (mb >= 2) ? rh1 : rh0;
            unsigned pk[2];
            #pragma unroll
            for (int h = 0; h < 2; h++) {
                float p0 = exp2f(sacc[mb][2 * h]     + rhv + rwc[(mb & 1) * 4 + 2 * h]);
                float p1 = exp2f(sacc[mb][2 * h + 1] + rhv + rwc[(mb & 1) * 4 + 2 * h + 1]);
                l_acc += p0; l_acc += p1;
                unsigned u0, u1;
                __builtin_memcpy(&u0, &p0, 4); __builtin_memcpy(&u1, &p1, 4);
                pk[h] = __builtin_amdgcn_perm(u1 + 0x8000u, u0 + 0x8000u, 0x07060302u);
            }
            uint2 u = {pk[0], pk[1]};
            *(uint2*)&pT[(w * 16 + lm) * LDT + mb * 16 + lq * 4] = u;   // wave-private rows
        }
        const bf16x8 pa0 = *(const bf16x8*)&pT[(w * 16 + lm) * LDT + lq * 8];
        const bf16x8 pa1 = *(const bf16x8*)&pT[(w * 16 + lm) * LDT + 32 + lq * 8];
        #pragma unroll
        for (int nb = 0; nb < 4; nb++) {
            bf16x8 vb0 = *(const bf16x8*)&vsT[(nb * 16 + lm) * 64 + lq * 8];
            bf16x8 vb1 = *(const bf16x8*)&vsT[(nb * 16 + lm) * 64 + 32 + lq * 8];
            oacc[nb] = __builtin_amdgcn_mfma_f32_16x16x32_bf16(pa0, vb0, oacc[nb], 0, 0, 0);
            oacc[nb] = __builtin_amdgcn_mfma_f32_16x16x32_bf16(pa1, vb1, oacc[nb], 0, 0, 0);
        }
    }
    l_acc += __shfl_xor(l_acc, 16);
    l_acc += __shfl_xor(l_acc, 32);
    const float rinv = 1.f / l_acc;
    float rv[4];
    #pragma unroll
    for (int rr = 0; rr < 4; rr++) rv[rr] = __shfl(rinv, lq * 4 + rr);
    const int bb = bn / 12, nh = bn % 12;
    #pragma unroll
    for (int nb = 0; nb < 4; nb++)
        #pragma unroll
        for (int rr = 0; rr < 4; rr++) {
            const int qrow = q0 + w * 16 + lq * 4 + rr;
            const int d = nb * 16 + lm;
            outb[((size_t)(bb * 1024 + qrow)) * 768 + nh * 64 + d] = f2b(oacc[nb][rr] * rv[rr]);
        }
}

// ---------------------------------------------------------------------------
extern "C" void kernel_launch(void* const* d_in, const int* in_sizes, int n_in,
                              void* d_out, int out_size, void* d_ws, size_t ws_size,
                              hipStream_t stream)
{
    u16* ws16  = (u16*)d_ws;
    u16* qkvT  = ws16;
    u16* xb    = ws16 + (size_t)18874368;
    u16* attn  = xb;                       // x dead after K1
    const size_t S = 25165824;
    u16* qkvw_b = ws16 + S;
    u16* projw_b = qkvw_b + 1769472;
    u16* qkvb_b = projw_b + 589824;
    u16* projb_b = qkvb_b + 2304;
    u16* relh_b = projb_b + 768;
    u16* relw_b = relh_b + 4032;
    int* flag = (int*)(ws16 + S + 2370432);

    detect_dtype<<<1, 64, 0, stream>>>((const u16*)d_in[0], flag);
    convert_in<<<6144, 256, 0, stream>>>(d_in[0], xb,      6291456, 1.0f,  flag);
    convert_in<<<1728, 256, 0, stream>>>(d_in[1], qkvw_b,  1769472, 1.0f,  flag);
    convert_in<<<9,    256, 0, stream>>>(d_in[2], qkvb_b,  2304,    1.0f,  flag);
    convert_in<<<576,  256, 0, stream>>>(d_in[3], projw_b, 589824,  1.0f,  flag);
    convert_in<<<3,    256, 0, stream>>>(d_in[4], projb_b, 768,     1.0f,  flag);
    convert_in<<<16,   256, 0, stream>>>(d_in[5], relh_b,  4032,    LOG2E, flag);
    convert_in<<<16,   256, 0, stream>>>(d_in[6], relw_b,  4032,    LOG2E, flag);

    gemm128<1><<<dim3(64, 18), 256, 0, stream>>>(xb, qkvw_b, qkvb_b, nullptr, flag, qkvT, 2304, 768);
    flash_attn_mfma<<<dim3(96, 16), 256, 0, stream>>>(qkvT, relh_b, relw_b, attn);
    gemm128<0><<<dim3(64, 6), 256, 0, stream>>>(attn, projw_b, projb_b, d_out, flag, nullptr, 768, 768);
}

// Round 7
// 283.217 us; speedup vs baseline: 1.0321x; 1.0048x over previous
//
#include <hip/hip_runtime.h>

// R7: store-scatter fix. R4-R6 invariant: qkv GEMM ~100-117us with MfmaUtil
// ~10%, VALU ~13%, HBM ~8% -- stall owned by no pipe = VMEM store-queue
// backpressure from per-element 2B scattered epilogue stores (V^T scatter =
// 6.3M isolated 2B stores at 2KB stride; q/k = 32B sectors). Fix: epilogue
// round-trips LDS (reuse 32KB staging tile) -> all global stores become
// 16B-coalesced uint4. K-loop (DMA staging), flash, proj, converts unchanged.

typedef unsigned short u16;
typedef __attribute__((ext_vector_type(8))) __bf16 bf16x8;
typedef __attribute__((ext_vector_type(4))) float f32x4;
typedef __attribute__((address_space(1))) const unsigned int gu32;
typedef __attribute__((address_space(3))) unsigned int lu32;

#define LOG2E 1.4426950408889634f

__device__ __forceinline__ float b2f(u16 u) {
    unsigned int i = ((unsigned int)u) << 16;
    float f; __builtin_memcpy(&f, &i, 4); return f;
}
__device__ __forceinline__ u16 f2b(float f) {
    unsigned int x; __builtin_memcpy(&x, &f, 4);
    x += 0x7fffu + ((x >> 16) & 1u);   // RTNE
    return (u16)(x >> 16);
}

#define LDT 72

// ---------------------------------------------------------------------------
__global__ void detect_dtype(const u16* __restrict__ x, int* __restrict__ flag)
{
    if (threadIdx.x == 0 && blockIdx.x == 0) {
        float mx = 0.f;
        for (int i = 0; i < 128; i++) {
            float v = fabsf(b2f(x[i]));
            if (!(v <= 1e30f)) v = 1e30f;
            mx = fmaxf(mx, v);
        }
        *flag = (mx > 1e4f) ? 1 : 0;
    }
}

__global__ __launch_bounds__(256) void convert_in(
    const void* __restrict__ src, u16* __restrict__ dst, int n, float scale,
    const int* __restrict__ flag)
{
    const int fl = *flag;
    for (int i = blockIdx.x * 256 + threadIdx.x; i < n; i += gridDim.x * 256) {
        float v = fl ? ((const float*)src)[i] : b2f(((const u16*)src)[i]);
        dst[i] = f2b(v * scale);
    }
}

// ---------------------------------------------------------------------------
// 128x128 GEMM (TN), BK=64, global_load_lds staging.
// EPI=0: proj (dual-dtype direct store, 64B-coalesced).
// EPI=1: qkv (rope + k-scale; outputs staged through LDS -> 16B uint4 stores).
// ---------------------------------------------------------------------------
template <int EPI>
__global__ __launch_bounds__(256) void gemm128(
    const u16* __restrict__ A, const u16* __restrict__ Bw,
    const u16* __restrict__ bias, void* __restrict__ Cout,
    const int* __restrict__ flag, u16* __restrict__ qkvT, int N, int K)
{
    __shared__ __align__(16) u16 smem[16384];    // lA[8192] | lB[8192]; reused as ct[128][128]
    u16* lA = smem;
    u16* lB = smem + 8192;
    u16* ct = smem;
    const int tid = threadIdx.x;
    const int m0 = blockIdx.x * 128, n0 = blockIdx.y * 128;
    const int wave = tid >> 6, lane = tid & 63;
    const int wm = (wave & 1) * 64, wn = (wave >> 1) * 64;
    const int lm = lane & 15, lq = lane >> 4;
    const int srow = lane >> 3, scol = (lane & 7) * 8;
    f32x4 acc[4][4] = {};
    for (int k0 = 0; k0 < K; k0 += 64) {
        if (k0) __syncthreads();
        #pragma unroll
        for (int c4 = 0; c4 < 4; c4++) {
            const int c = wave * 4 + c4;
            const int row = c * 8 + srow;
            __builtin_amdgcn_global_load_lds(
                (gu32*)(A + (size_t)(m0 + row) * K + k0 + scol),
                (lu32*)&lA[c * 512], 16, 0, 0);
            __builtin_amdgcn_global_load_lds(
                (gu32*)(Bw + (size_t)(n0 + row) * K + k0 + scol),
                (lu32*)&lB[c * 512], 16, 0, 0);
        }
        __syncthreads();
        #pragma unroll
        for (int ks = 0; ks < 64; ks += 32) {
            bf16x8 af[4], bfr[4];
            #pragma unroll
            for (int i = 0; i < 4; i++) af[i]  = *(const bf16x8*)&lA[(wm + i * 16 + lm) * 64 + ks + lq * 8];
            #pragma unroll
            for (int j = 0; j < 4; j++) bfr[j] = *(const bf16x8*)&lB[(wn + j * 16 + lm) * 64 + ks + lq * 8];
            #pragma unroll
            for (int i = 0; i < 4; i++)
                #pragma unroll
                for (int j = 0; j < 4; j++)
                    acc[i][j] = __builtin_amdgcn_mfma_f32_16x16x32_bf16(af[i], bfr[j], acc[i][j], 0, 0, 0);
        }
    }
    if (EPI == 0) {
        const int fl = *flag;
        #pragma unroll
        for (int i = 0; i < 4; i++)
            #pragma unroll
            for (int j = 0; j < 4; j++)
                #pragma unroll
                for (int r = 0; r < 4; r++) {
                    const int m = m0 + wm + i * 16 + lq * 4 + r;
                    const int n = n0 + wn + j * 16 + lm;
                    const float v = acc[i][j][r] + b2f(bias[n]);
                    if (fl) ((float*)Cout)[(size_t)m * 768 + n] = v;
                    else    ((u16*)Cout)[(size_t)m * 768 + n] = f2b(v);
                }
    } else {
        const int which = n0 / 768;
        const bool vt = (which == 2);
        __syncthreads();                         // K-loop LDS readers done; reuse smem
        #pragma unroll
        for (int i = 0; i < 4; i++)
            #pragma unroll
            for (int j = 0; j < 4; j++)
                #pragma unroll
                for (int r = 0; r < 4; r++) {
                    const int ml = wm + i * 16 + lq * 4 + r;
                    const int nl = wn + j * 16 + lm;
                    const int m = m0 + ml, n = n0 + nl;
                    float v = acc[i][j][r] + b2f(bias[n]);
                    const float p = __shfl_xor(v, 1);      // rope pair partner
                    const int l = m & 1023, d = n & 63;
                    float o = v;
                    if (which < 2) {
                        const int pi = d >> 1, jj = pi & 15;
                        const float coord = (pi < 16) ? (float)(l & 31) : (float)(l >> 5);
                        const float ang = coord * __expf(-(float)jj * 0.5756462732485115f);
                        float sn, cs; __sincosf(ang, &sn, &cs);
                        o = v * cs + ((d & 1) ? p * sn : -(p * sn));
                        if (which == 1) o *= 0.125f * LOG2E;
                    }
                    ct[vt ? nl * 128 + ml : ml * 128 + nl] = f2b(o);
                }
        __syncthreads();
        const size_t HL = (size_t)96 * 1024 * 64;
        const int nh0 = (n0 >> 6) % 12, bb = m0 >> 10, l0 = m0 & 1023;
        if (!vt) {
            // runs: (m_local, head) -> 128B contiguous global, 8 lanes x 16B
            #pragma unroll
            for (int pass = 0; pass < 8; pass++) {
                const int chunk = pass * 256 + tid;
                const int run = chunk >> 3, lc = chunk & 7;
                const int ml = run >> 1, h = run & 1;
                u16* gp = qkvT + (size_t)which * HL
                        + ((size_t)(bb * 12 + nh0 + h) * 1024 + l0 + ml) * 64 + lc * 8;
                *(uint4*)gp = *(const uint4*)&ct[ml * 128 + h * 64 + lc * 8];
            }
        } else {
            // runs: (head,d) rows -> 256B contiguous global over l, 16 lanes x 16B
            #pragma unroll
            for (int pass = 0; pass < 8; pass++) {
                const int run = pass * 16 + (tid >> 4), ln = tid & 15;
                u16* gp = qkvT + 2 * HL
                        + (size_t)(bb * 12 + nh0 + (run >> 6)) * 65536
                        + (size_t)(run & 63) * 1024 + l0 + ln * 8;
                *(uint4*)gp = *(const uint4*)&ct[run * 128 + ln * 8];
            }
        }
    }
}

// ---------------------------------------------------------------------------
// K2: MFMA flash attention (unchanged from R6)
// ---------------------------------------------------------------------------
__global__ __launch_bounds__(256) void flash_attn_mfma(
    const u16* __restrict__ qkvT, const u16* __restrict__ relH,
    const u16* __restrict__ relW, u16* __restrict__ outb)
{
    __shared__ __align__(16) u16 ks2[64 * 64];
    __shared__ __align__(16) u16 vsT[64 * 64];
    __shared__ __align__(16) u16 qs[64 * LDT];
    __shared__ __align__(16) u16 Th[64 * LDT];
    __shared__ __align__(16) u16 Tw[64 * LDT];
    u16* rel = vsT;
    u16* pT  = qs;

    const int tid = threadIdx.x;
    const int bn = blockIdx.x, q0 = blockIdx.y * 64;
    const size_t HL = (size_t)96 * 1024 * 64;
    const u16* qg  = qkvT + (size_t)bn * 65536 + (size_t)q0 * 64;
    const u16* kgb = qkvT + HL + (size_t)bn * 65536;
    const u16* vTg = qkvT + 2 * HL + (size_t)bn * 65536;

    for (int g = tid; g < 1024; g += 256) {
        int r = g >> 4, c = (g & 15) * 4;
        *(ushort4*)&qs[r * LDT + c] = ((const ushort4*)qg)[g];
    }
    for (int g = tid; g < 1008; g += 256) {
        int r = g >> 4, c = (g & 15) * 4;
        *(ushort4*)&rel[r * 64 + c] = *(const ushort4*)(relH + g * 4);
    }
    if (tid < 16) { ushort4 z = {0, 0, 0, 0}; *(ushort4*)&rel[63 * 64 + tid * 4] = z; }
    __syncthreads();

    const int w = tid >> 6, lane = tid & 63;
    const int lm = lane & 15, lq = lane >> 4;

    const bf16x8 bq0 = *(const bf16x8*)&qs[(w * 16 + lm) * LDT + lq * 8];
    const bf16x8 bq1 = *(const bf16x8*)&qs[(w * 16 + lm) * LDT + 32 + lq * 8];

    {   // Th = Q . relH^T
        f32x4 tacc[4] = {};
        #pragma unroll
        for (int nb = 0; nb < 4; nb++) {
            bf16x8 r0 = *(const bf16x8*)&rel[(nb * 16 + lm) * 64 + lq * 8];
            bf16x8 r1 = *(const bf16x8*)&rel[(nb * 16 + lm) * 64 + 32 + lq * 8];
            tacc[nb] = __builtin_amdgcn_mfma_f32_16x16x32_bf16(bq0, r0, tacc[nb], 0, 0, 0);
            tacc[nb] = __builtin_amdgcn_mfma_f32_16x16x32_bf16(bq1, r1, tacc[nb], 0, 0, 0);
        }
        #pragma unroll
        for (int nb = 0; nb < 4; nb++)
            #pragma unroll
            for (int rr = 0; rr < 4; rr++)
                Th[(w * 16 + lq * 4 + rr) * LDT + nb * 16 + lm] = f2b(tacc[nb][rr]);
    }
    __syncthreads();
    for (int g = tid; g < 1008; g += 256) {
        int r = g >> 4, c = (g & 15) * 4;
        *(ushort4*)&rel[r * 64 + c] = *(const ushort4*)(relW + g * 4);
    }
    if (tid < 16) { ushort4 z = {0, 0, 0, 0}; *(ushort4*)&rel[63 * 64 + tid * 4] = z; }
    __syncthreads();
    {   // Tw = Q . relW^T
        f32x4 tacc[4] = {};
        #pragma unroll
        for (int nb = 0; nb < 4; nb++) {
            bf16x8 r0 = *(const bf16x8*)&rel[(nb * 16 + lm) * 64 + lq * 8];
            bf16x8 r1 = *(const bf16x8*)&rel[(nb * 16 + lm) * 64 + 32 + lq * 8];
            tacc[nb] = __builtin_amdgcn_mfma_f32_16x16x32_bf16(bq0, r0, tacc[nb], 0, 0, 0);
            tacc[nb] = __builtin_amdgcn_mfma_f32_16x16x32_bf16(bq1, r1, tacc[nb], 0, 0, 0);
        }
        #pragma unroll
        for (int nb = 0; nb < 4; nb++)
            #pragma unroll
            for (int rr = 0; rr < 4; rr++)
                Tw[(w * 16 + lq * 4 + rr) * LDT + nb * 16 + lm] = f2b(tacc[nb][rr]);
    }
    const int qw = (w & 1) * 16 + lm;
    float rwc[8];
    #pragma unroll
    for (int mb2 = 0; mb2 < 2; mb2++)
        #pragma unroll
        for (int rr = 0; rr < 4; rr++) {
            const int kw = mb2 * 16 + lq * 4 + rr;
            rwc[mb2 * 4 + rr] = b2f(Tw[(w * 16 + lm) * LDT + qw - kw + 31]) - 16.0f;
        }
    const int qh = (q0 >> 5) + (w >= 2 ? 1 : 0);

    const int srow = lane >> 3, scol = (lane & 7) * 8;
    float l_acc = 0.f;
    f32x4 oacc[4] = {};

    #pragma unroll 1
    for (int kt = 0; kt < 16; kt++) {
        __syncthreads();
        const u16* kp = kgb + (size_t)kt * 4096;
        #pragma unroll
        for (int c4 = 0; c4 < 2; c4++) {
            const int c = w * 2 + c4;
            const int row = c * 8 + srow;
            __builtin_amdgcn_global_load_lds(
                (gu32*)(kp + row * 64 + scol), (lu32*)&ks2[c * 512], 16, 0, 0);
            __builtin_amdgcn_global_load_lds(
                (gu32*)(vTg + (size_t)row * 1024 + kt * 64 + scol), (lu32*)&vsT[c * 512], 16, 0, 0);
        }
        __syncthreads();
        f32x4 sacc[4];
        #pragma unroll
        for (int mb = 0; mb < 4; mb++) {
            bf16x8 ka0 = *(const bf16x8*)&ks2[(mb * 16 + lm) * 64 + lq * 8];
            bf16x8 ka1 = *(const bf16x8*)&ks2[(mb * 16 + lm) * 64 + 32 + lq * 8];
            f32x4 s = {};
            s = __builtin_amdgcn_mfma_f32_16x16x32_bf16(ka0, bq0, s, 0, 0, 0);
            s = __builtin_amdgcn_mfma_f32_16x16x32_bf16(ka1, bq1, s, 0, 0, 0);
            sacc[mb] = s;
        }
        const float rh0 = b2f(Th[(w * 16 + lm) * LDT + qh - 2 * kt + 31]);
        const float rh1 = b2f(Th[(w * 16 + lm) * LDT + qh - 2 * kt + 30]);
        #pragma unroll
        for (int mb = 0; mb < 4; mb++) {
            const float rhv = (mb >= 2) ? rh1 : rh0;
            unsigned pk[2];
            #pragma unroll
            for (int h = 0; h < 2; h++) {
                float p0 = exp2f(sacc[mb][2 * h]     + rhv + rwc[(mb & 1) * 4 + 2 * h]);
                float p1 = exp2f(sacc[mb][2 * h + 1] + rhv + rwc[(mb & 1) * 4 + 2 * h + 1]);
                l_acc += p0; l_acc += p1;
                unsigned u0, u1;
                __builtin_memcpy(&u0, &p0, 4); __builtin_memcpy(&u1, &p1, 4);
                pk[h] = __builtin_amdgcn_perm(u1 + 0x8000u, u0 + 0x8000u, 0x07060302u);
            }
            uint2 u = {pk[0], pk[1]};
            *(uint2*)&pT[(w * 16 + lm) * LDT + mb * 16 + lq * 4] = u;
        }
        const bf16x8 pa0 = *(const bf16x8*)&pT[(w * 16 + lm) * LDT + lq * 8];
        const bf16x8 pa1 = *(const bf16x8*)&pT[(w * 16 + lm) * LDT + 32 + lq * 8];
        #pragma unroll
        for (int nb = 0; nb < 4; nb++) {
            bf16x8 vb0 = *(const bf16x8*)&vsT[(nb * 16 + lm) * 64 + lq * 8];
            bf16x8 vb1 = *(const bf16x8*)&vsT[(nb * 16 + lm) * 64 + 32 + lq * 8];
            oacc[nb] = __builtin_amdgcn_mfma_f32_16x16x32_bf16(pa0, vb0, oacc[nb], 0, 0, 0);
            oacc[nb] = __builtin_amdgcn_mfma_f32_16x16x32_bf16(pa1, vb1, oacc[nb], 0, 0, 0);
        }
    }
    l_acc += __shfl_xor(l_acc, 16);
    l_acc += __shfl_xor(l_acc, 32);
    const float rinv = 1.f / l_acc;
    float rv[4];
    #pragma unroll
    for (int rr = 0; rr < 4; rr++) rv[rr] = __shfl(rinv, lq * 4 + rr);
    const int bb = bn / 12, nh = bn % 12;
    #pragma unroll
    for (int nb = 0; nb < 4; nb++)
        #pragma unroll
        for (int rr = 0; rr < 4; rr++) {
            const int qrow = q0 + w * 16 + lq * 4 + rr;
            const int d = nb * 16 + lm;
            outb[((size_t)(bb * 1024 + qrow)) * 768 + nh * 64 + d] = f2b(oacc[nb][rr] * rv[rr]);
        }
}

// ---------------------------------------------------------------------------
extern "C" void kernel_launch(void* const* d_in, const int* in_sizes, int n_in,
                              void* d_out, int out_size, void* d_ws, size_t ws_size,
                              hipStream_t stream)
{
    u16* ws16  = (u16*)d_ws;
    u16* qkvT  = ws16;
    u16* xb    = ws16 + (size_t)18874368;
    u16* attn  = xb;                       // x dead after K1
    const size_t S = 25165824;
    u16* qkvw_b = ws16 + S;
    u16* projw_b = qkvw_b + 1769472;
    u16* qkvb_b = projw_b + 589824;
    u16* projb_b = qkvb_b + 2304;
    u16* relh_b = projb_b + 768;
    u16* relw_b = relh_b + 4032;
    int* flag = (int*)(ws16 + S + 2370432);

    detect_dtype<<<1, 64, 0, stream>>>((const u16*)d_in[0], flag);
    convert_in<<<6144, 256, 0, stream>>>(d_in[0], xb,      6291456, 1.0f,  flag);
    convert_in<<<1728, 256, 0, stream>>>(d_in[1], qkvw_b,  1769472, 1.0f,  flag);
    convert_in<<<9,    256, 0, stream>>>(d_in[2], qkvb_b,  2304,    1.0f,  flag);
    convert_in<<<576,  256, 0, stream>>>(d_in[3], projw_b, 589824,  1.0f,  flag);
    convert_in<<<3,    256, 0, stream>>>(d_in[4], projb_b, 768,     1.0f,  flag);
    convert_in<<<16,   256, 0, stream>>>(d_in[5], relh_b,  4032,    LOG2E, flag);
    convert_in<<<16,   256, 0, stream>>>(d_in[6], relw_b,  4032,    LOG2E, flag);

    gemm128<1><<<dim3(64, 18), 256, 0, stream>>>(xb, qkvw_b, qkvb_b, nullptr, flag, qkvT, 2304, 768);
    flash_attn_mfma<<<dim3(96, 16), 256, 0, stream>>>(qkvT, relh_b, relw_b, attn);
    gemm128<0><<<dim3(64, 6), 256, 0, stream>>>(attn, projw_b, projb_b, d_out, flag, nullptr, 768, 768);
}

// Round 8
// 269.480 us; speedup vs baseline: 1.0847x; 1.0510x over previous
//
#include <hip/hip_runtime.h>

// R8: V^T layout fix. Five-round correlation: every kernel writing V^T as
// [bn][d][l] (256B runs @ 2KB stride over 24MB) is stuck at ~100us with all
// pipes idle; R3's [l][d]-only epilogue was fast. R7 falsified store *width*
// (ideal WRITE_SIZE, no change) -> the *pattern* is the poison. New layout:
// V^T[bn][kt][d][l64] -- flash reads one sequential 8KB block per tile
// (same address math as K tile); GEMM writes contiguous 32KB per block.
// Also: 8 convert launches -> 1; bias loads hoisted 16->4 per thread.

typedef unsigned short u16;
typedef __attribute__((ext_vector_type(8))) __bf16 bf16x8;
typedef __attribute__((ext_vector_type(4))) float f32x4;
typedef __attribute__((address_space(1))) const unsigned int gu32;
typedef __attribute__((address_space(3))) unsigned int lu32;

#define LOG2E 1.4426950408889634f

__device__ __forceinline__ float b2f(u16 u) {
    unsigned int i = ((unsigned int)u) << 16;
    float f; __builtin_memcpy(&f, &i, 4); return f;
}
__device__ __forceinline__ u16 f2b(float f) {
    unsigned int x; __builtin_memcpy(&x, &f, 4);
    x += 0x7fffu + ((x >> 16) & 1u);   // RTNE
    return (u16)(x >> 16);
}

#define LDT 72

// ---------------------------------------------------------------------------
__global__ void detect_dtype(const u16* __restrict__ x, int* __restrict__ flag)
{
    if (threadIdx.x == 0 && blockIdx.x == 0) {
        float mx = 0.f;
        for (int i = 0; i < 128; i++) {
            float v = fabsf(b2f(x[i]));
            if (!(v <= 1e30f)) v = 1e30f;
            mx = fmaxf(mx, v);
        }
        *flag = (mx > 1e4f) ? 1 : 0;
    }
}

struct CvtArgs {
    const void* src[7];
    u16*        dst[7];
    int         n[7];
    float       sc[7];
};

__global__ __launch_bounds__(256) void convert_all(CvtArgs a, const int* __restrict__ flag)
{
    const int fl = *flag;
    const int g = blockIdx.x * 256 + threadIdx.x;
    const int stride = gridDim.x * 256;
    #pragma unroll 1
    for (int s = 0; s < 7; s++) {
        const int n = a.n[s];
        const float sc = a.sc[s];
        const float* fs = (const float*)a.src[s];
        const u16*  hs = (const u16*)a.src[s];
        u16* d = a.dst[s];
        for (int i = g; i < n; i += stride) {
            float v = fl ? fs[i] : b2f(hs[i]);
            d[i] = f2b(v * sc);
        }
    }
}

// ---------------------------------------------------------------------------
// 128x128 GEMM (TN), BK=64, global_load_lds staging.
// EPI=0: proj (dual-dtype direct store).
// EPI=1: qkv. q,k -> [which][bn][l][d]; V -> [bn][kt][d][l64] (tile-major,
//        fully contiguous per 64-l tile). All stores via LDS + uint4.
// ---------------------------------------------------------------------------
template <int EPI>
__global__ __launch_bounds__(256) void gemm128(
    const u16* __restrict__ A, const u16* __restrict__ Bw,
    const u16* __restrict__ bias, void* __restrict__ Cout,
    const int* __restrict__ flag, u16* __restrict__ qkvT, int N, int K)
{
    __shared__ __align__(16) u16 smem[16384];    // lA|lB; reused as ct[128][128]
    u16* lA = smem;
    u16* lB = smem + 8192;
    u16* ct = smem;
    const int tid = threadIdx.x;
    const int m0 = blockIdx.x * 128, n0 = blockIdx.y * 128;
    const int wave = tid >> 6, lane = tid & 63;
    const int wm = (wave & 1) * 64, wn = (wave >> 1) * 64;
    const int lm = lane & 15, lq = lane >> 4;
    const int srow = lane >> 3, scol = (lane & 7) * 8;
    f32x4 acc[4][4] = {};
    for (int k0 = 0; k0 < K; k0 += 64) {
        if (k0) __syncthreads();
        #pragma unroll
        for (int c4 = 0; c4 < 4; c4++) {
            const int c = wave * 4 + c4;
            const int row = c * 8 + srow;
            __builtin_amdgcn_global_load_lds(
                (gu32*)(A + (size_t)(m0 + row) * K + k0 + scol),
                (lu32*)&lA[c * 512], 16, 0, 0);
            __builtin_amdgcn_global_load_lds(
                (gu32*)(Bw + (size_t)(n0 + row) * K + k0 + scol),
                (lu32*)&lB[c * 512], 16, 0, 0);
        }
        __syncthreads();
        #pragma unroll
        for (int ks = 0; ks < 64; ks += 32) {
            bf16x8 af[4], bfr[4];
            #pragma unroll
            for (int i = 0; i < 4; i++) af[i]  = *(const bf16x8*)&lA[(wm + i * 16 + lm) * 64 + ks + lq * 8];
            #pragma unroll
            for (int j = 0; j < 4; j++) bfr[j] = *(const bf16x8*)&lB[(wn + j * 16 + lm) * 64 + ks + lq * 8];
            #pragma unroll
            for (int i = 0; i < 4; i++)
                #pragma unroll
                for (int j = 0; j < 4; j++)
                    acc[i][j] = __builtin_amdgcn_mfma_f32_16x16x32_bf16(af[i], bfr[j], acc[i][j], 0, 0, 0);
        }
    }
    if (EPI == 0) {
        const int fl = *flag;
        #pragma unroll
        for (int j = 0; j < 4; j++) {
            const int n = n0 + wn + j * 16 + lm;
            const float bj = b2f(bias[n]);
            #pragma unroll
            for (int i = 0; i < 4; i++)
                #pragma unroll
                for (int r = 0; r < 4; r++) {
                    const int m = m0 + wm + i * 16 + lq * 4 + r;
                    const float v = acc[i][j][r] + bj;
                    if (fl) ((float*)Cout)[(size_t)m * 768 + n] = v;
                    else    ((u16*)Cout)[(size_t)m * 768 + n] = f2b(v);
                }
        }
    } else {
        const int which = n0 / 768;
        const bool vt = (which == 2);
        __syncthreads();                         // K-loop LDS readers done; reuse smem
        #pragma unroll
        for (int j = 0; j < 4; j++) {
            const int nl = wn + j * 16 + lm;
            const int n = n0 + nl;
            const float bj = b2f(bias[n]);
            #pragma unroll
            for (int i = 0; i < 4; i++)
                #pragma unroll
                for (int r = 0; r < 4; r++) {
                    const int ml = wm + i * 16 + lq * 4 + r;
                    const int m = m0 + ml;
                    float v = acc[i][j][r] + bj;
                    const float p = __shfl_xor(v, 1);      // rope pair partner
                    const int l = m & 1023, d = n & 63;
                    float o = v;
                    if (which < 2) {
                        const int pi = d >> 1, jj = pi & 15;
                        const float coord = (pi < 16) ? (float)(l & 31) : (float)(l >> 5);
                        const float ang = coord * __expf(-(float)jj * 0.5756462732485115f);
                        float sn, cs; __sincosf(ang, &sn, &cs);
                        o = v * cs + ((d & 1) ? p * sn : -(p * sn));
                        if (which == 1) o *= 0.125f * LOG2E;
                    }
                    ct[vt ? nl * 128 + ml : ml * 128 + nl] = f2b(o);
                }
        }
        __syncthreads();
        const size_t HL = (size_t)96 * 1024 * 64;
        const int nh0 = (n0 >> 6) % 12, bb = m0 >> 10, l0 = m0 & 1023;
        if (!vt) {
            // (l, head) runs -> 128B contiguous, 8 lanes x 16B
            #pragma unroll
            for (int pass = 0; pass < 8; pass++) {
                const int chunk = pass * 256 + tid;
                const int run = chunk >> 3, lc = chunk & 7;
                const int ml = run >> 1, h = run & 1;
                u16* gp = qkvT + (size_t)which * HL
                        + ((size_t)(bb * 12 + nh0 + h) * 1024 + l0 + ml) * 64 + lc * 8;
                *(uint4*)gp = *(const uint4*)&ct[ml * 128 + h * 64 + lc * 8];
            }
        } else {
            // V^T tiled: [bn][kt][d][l64]; block covers kt0,kt0+1 x 2 heads,
            // each (h,kt) a contiguous 8KB block. 128B contiguous per 8 lanes.
            const int kt0 = l0 >> 6;
            #pragma unroll
            for (int pass = 0; pass < 8; pass++) {
                const int run = pass * 16 + (tid >> 4);       // h*64 + d
                const int ln = tid & 15;
                const int half = ln >> 3, l8 = ln & 7;
                u16* gp = qkvT + 2 * HL
                        + (size_t)(bb * 12 + nh0 + (run >> 6)) * 65536
                        + (size_t)(kt0 + half) * 4096 + (run & 63) * 64 + l8 * 8;
                *(uint4*)gp = *(const uint4*)&ct[run * 128 + ln * 8];
            }
        }
    }
}

// ---------------------------------------------------------------------------
// K2: MFMA flash attention; V^T now tile-contiguous (same DMA math as K).
// ---------------------------------------------------------------------------
__global__ __launch_bounds__(256) void flash_attn_mfma(
    const u16* __restrict__ qkvT, const u16* __restrict__ relH,
    const u16* __restrict__ relW, u16* __restrict__ outb)
{
    __shared__ __align__(16) u16 ks2[64 * 64];
    __shared__ __align__(16) u16 vsT[64 * 64];
    __shared__ __align__(16) u16 qs[64 * LDT];
    __shared__ __align__(16) u16 Th[64 * LDT];
    __shared__ __align__(16) u16 Tw[64 * LDT];
    u16* rel = vsT;
    u16* pT  = qs;

    const int tid = threadIdx.x;
    const int bn = blockIdx.x, q0 = blockIdx.y * 64;
    const size_t HL = (size_t)96 * 1024 * 64;
    const u16* qg  = qkvT + (size_t)bn * 65536 + (size_t)q0 * 64;
    const u16* kgb = qkvT + HL + (size_t)bn * 65536;
    const u16* vgb = qkvT + 2 * HL + (size_t)bn * 65536;   // [kt][d][l64] tiled

    for (int g = tid; g < 1024; g += 256) {
        int r = g >> 4, c = (g & 15) * 4;
        *(ushort4*)&qs[r * LDT + c] = ((const ushort4*)qg)[g];
    }
    for (int g = tid; g < 1008; g += 256) {
        int r = g >> 4, c = (g & 15) * 4;
        *(ushort4*)&rel[r * 64 + c] = *(const ushort4*)(relH + g * 4);
    }
    if (tid < 16) { ushort4 z = {0, 0, 0, 0}; *(ushort4*)&rel[63 * 64 + tid * 4] = z; }
    __syncthreads();

    const int w = tid >> 6, lane = tid & 63;
    const int lm = lane & 15, lq = lane >> 4;

    const bf16x8 bq0 = *(const bf16x8*)&qs[(w * 16 + lm) * LDT + lq * 8];
    const bf16x8 bq1 = *(const bf16x8*)&qs[(w * 16 + lm) * LDT + 32 + lq * 8];

    {   // Th = Q . relH^T
        f32x4 tacc[4] = {};
        #pragma unroll
        for (int nb = 0; nb < 4; nb++) {
            bf16x8 r0 = *(const bf16x8*)&rel[(nb * 16 + lm) * 64 + lq * 8];
            bf16x8 r1 = *(const bf16x8*)&rel[(nb * 16 + lm) * 64 + 32 + lq * 8];
            tacc[nb] = __builtin_amdgcn_mfma_f32_16x16x32_bf16(bq0, r0, tacc[nb], 0, 0, 0);
            tacc[nb] = __builtin_amdgcn_mfma_f32_16x16x32_bf16(bq1, r1, tacc[nb], 0, 0, 0);
        }
        #pragma unroll
        for (int nb = 0; nb < 4; nb++)
            #pragma unroll
            for (int rr = 0; rr < 4; rr++)
                Th[(w * 16 + lq * 4 + rr) * LDT + nb * 16 + lm] = f2b(tacc[nb][rr]);
    }
    __syncthreads();
    for (int g = tid; g < 1008; g += 256) {
        int r = g >> 4, c = (g & 15) * 4;
        *(ushort4*)&rel[r * 64 + c] = *(const ushort4*)(relW + g * 4);
    }
    if (tid < 16) { ushort4 z = {0, 0, 0, 0}; *(ushort4*)&rel[63 * 64 + tid * 4] = z; }
    __syncthreads();
    {   // Tw = Q . relW^T
        f32x4 tacc[4] = {};
        #pragma unroll
        for (int nb = 0; nb < 4; nb++) {
            bf16x8 r0 = *(const bf16x8*)&rel[(nb * 16 + lm) * 64 + lq * 8];
            bf16x8 r1 = *(const bf16x8*)&rel[(nb * 16 + lm) * 64 + 32 + lq * 8];
            tacc[nb] = __builtin_amdgcn_mfma_f32_16x16x32_bf16(bq0, r0, tacc[nb], 0, 0, 0);
            tacc[nb] = __builtin_amdgcn_mfma_f32_16x16x32_bf16(bq1, r1, tacc[nb], 0, 0, 0);
        }
        #pragma unroll
        for (int nb = 0; nb < 4; nb++)
            #pragma unroll
            for (int rr = 0; rr < 4; rr++)
                Tw[(w * 16 + lq * 4 + rr) * LDT + nb * 16 + lm] = f2b(tacc[nb][rr]);
    }
    const int qw = (w & 1) * 16 + lm;
    float rwc[8];
    #pragma unroll
    for (int mb2 = 0; mb2 < 2; mb2++)
        #pragma unroll
        for (int rr = 0; rr < 4; rr++) {
            const int kw = mb2 * 16 + lq * 4 + rr;
            rwc[mb2 * 4 + rr] = b2f(Tw[(w * 16 + lm) * LDT + qw - kw + 31]) - 16.0f;
        }
    const int qh = (q0 >> 5) + (w >= 2 ? 1 : 0);

    const int srow = lane >> 3, scol = (lane & 7) * 8;
    float l_acc = 0.f;
    f32x4 oacc[4] = {};

    #pragma unroll 1
    for (int kt = 0; kt < 16; kt++) {
        __syncthreads();
        const u16* kp = kgb + (size_t)kt * 4096;
        const u16* vp = vgb + (size_t)kt * 4096;
        #pragma unroll
        for (int c4 = 0; c4 < 2; c4++) {
            const int c = w * 2 + c4;
            const int row = c * 8 + srow;
            __builtin_amdgcn_global_load_lds(
                (gu32*)(kp + row * 64 + scol), (lu32*)&ks2[c * 512], 16, 0, 0);
            __builtin_amdgcn_global_load_lds(
                (gu32*)(vp + row * 64 + scol), (lu32*)&vsT[c * 512], 16, 0, 0);
        }
        __syncthreads();
        f32x4 sacc[4];
        #pragma unroll
        for (int mb = 0; mb < 4; mb++) {
            bf16x8 ka0 = *(const bf16x8*)&ks2[(mb * 16 + lm) * 64 + lq * 8];
            bf16x8 ka1 = *(const bf16x8*)&ks2[(mb * 16 + lm) * 64 + 32 + lq * 8];
            f32x4 s = {};
            s = __builtin_amdgcn_mfma_f32_16x16x32_bf16(ka0, bq0, s, 0, 0, 0);
            s = __builtin_amdgcn_mfma_f32_16x16x32_bf16(ka1, bq1, s, 0, 0, 0);
            sacc[mb] = s;
        }
        const float rh0 = b2f(Th[(w * 16 + lm) * LDT + qh - 2 * kt + 31]);
        const float rh1 = b2f(Th[(w * 16 + lm) * LDT + qh - 2 * kt + 30]);
        #pragma unroll
        for (int mb = 0; mb < 4; mb++) {
            const float rhv = (mb >= 2) ? rh1 : rh0;
            unsigned pk[2];
            #pragma unroll
            for (int h = 0; h < 2; h++) {
                float p0 = exp2f(sacc[mb][2 * h]     + rhv + rwc[(mb & 1) * 4 + 2 * h]);
                float p1 = exp2f(sacc[mb][2 * h + 1] + rhv + rwc[(mb & 1) * 4 + 2 * h + 1]);
                l_acc += p0; l_acc += p1;
                unsigned u0, u1;
                __builtin_memcpy(&u0, &p0, 4); __builtin_memcpy(&u1, &p1, 4);
                pk[h] = __builtin_amdgcn_perm(u1 + 0x8000u, u0 + 0x8000u, 0x07060302u);
            }
            uint2 u = {pk[0], pk[1]};
            *(uint2*)&pT[(w * 16 + lm) * LDT + mb * 16 + lq * 4] = u;
        }
        const bf16x8 pa0 = *(const bf16x8*)&pT[(w * 16 + lm) * LDT + lq * 8];
        const bf16x8 pa1 = *(const bf16x8*)&pT[(w * 16 + lm) * LDT + 32 + lq * 8];
        #pragma unroll
        for (int nb = 0; nb < 4; nb++) {
            bf16x8 vb0 = *(const bf16x8*)&vsT[(nb * 16 + lm) * 64 + lq * 8];
            bf16x8 vb1 = *(const bf16x8*)&vsT[(nb * 16 + lm) * 64 + 32 + lq * 8];
            oacc[nb] = __builtin_amdgcn_mfma_f32_16x16x32_bf16(pa0, vb0, oacc[nb], 0, 0, 0);
            oacc[nb] = __builtin_amdgcn_mfma_f32_16x16x32_bf16(pa1, vb1, oacc[nb], 0, 0, 0);
        }
    }
    l_acc += __shfl_xor(l_acc, 16);
    l_acc += __shfl_xor(l_acc, 32);
    const float rinv = 1.f / l_acc;
    float rv[4];
    #pragma unroll
    for (int rr = 0; rr < 4; rr++) rv[rr] = __shfl(rinv, lq * 4 + rr);
    const int bb = bn / 12, nh = bn % 12;
    #pragma unroll
    for (int nb = 0; nb < 4; nb++)
        #pragma unroll
        for (int rr = 0; rr < 4; rr++) {
            const int qrow = q0 + w * 16 + lq * 4 + rr;
            const int d = nb * 16 + lm;
            outb[((size_t)(bb * 1024 + qrow)) * 768 + nh * 64 + d] = f2b(oacc[nb][rr] * rv[rr]);
        }
}

// ---------------------------------------------------------------------------
extern "C" void kernel_launch(void* const* d_in, const int* in_sizes, int n_in,
                              void* d_out, int out_size, void* d_ws, size_t ws_size,
                              hipStream_t stream)
{
    u16* ws16  = (u16*)d_ws;
    u16* qkvT  = ws16;
    u16* xb    = ws16 + (size_t)18874368;
    u16* attn  = xb;                       // x dead after K1
    const size_t S = 25165824;
    u16* qkvw_b = ws16 + S;
    u16* projw_b = qkvw_b + 1769472;
    u16* qkvb_b = projw_b + 589824;
    u16* projb_b = qkvb_b + 2304;
    u16* relh_b = projb_b + 768;
    u16* relw_b = relh_b + 4032;
    int* flag = (int*)(ws16 + S + 2370432);

    detect_dtype<<<1, 64, 0, stream>>>((const u16*)d_in[0], flag);

    CvtArgs ca;
    ca.src[0] = d_in[0]; ca.dst[0] = xb;      ca.n[0] = 6291456; ca.sc[0] = 1.0f;
    ca.src[1] = d_in[1]; ca.dst[1] = qkvw_b;  ca.n[1] = 1769472; ca.sc[1] = 1.0f;
    ca.src[2] = d_in[3]; ca.dst[2] = projw_b; ca.n[2] = 589824;  ca.sc[2] = 1.0f;
    ca.src[3] = d_in[2]; ca.dst[3] = qkvb_b;  ca.n[3] = 2304;    ca.sc[3] = 1.0f;
    ca.src[4] = d_in[4]; ca.dst[4] = projb_b; ca.n[4] = 768;     ca.sc[4] = 1.0f;
    ca.src[5] = d_in[5]; ca.dst[5] = relh_b;  ca.n[5] = 4032;    ca.sc[5] = LOG2E;
    ca.src[6] = d_in[6]; ca.dst[6] = relw_b;  ca.n[6] = 4032;    ca.sc[6] = LOG2E;
    convert_all<<<2048, 256, 0, stream>>>(ca, flag);

    gemm128<1><<<dim3(64, 18), 256, 0, stream>>>(xb, qkvw_b, qkvb_b, nullptr, flag, qkvT, 2304, 768);
    flash_attn_mfma<<<dim3(96, 16), 256, 0, stream>>>(qkvT, relh_b, relw_b, attn);
    gemm128<0><<<dim3(64, 6), 256, 0, stream>>>(attn, projw_b, projb_b, d_out, flag, nullptr, 768, 768);
}

// Round 9
// 249.272 us; speedup vs baseline: 1.1726x; 1.0811x over previous
//
#include <hip/hip_runtime.h>

// R9: (1) XOR-swizzled global_load_lds staging in BOTH gemm128 and flash
// (ks2/vsT/lA/lB row stride = 32 banks -> 16-way conflict on every b128 frag
// read; 2.29e7 conflict cycles = ~37us of flash's 90us). Swizzle: global col
// c16^(row&7) -> LDS slot c16; banks become f(col16) only -> 2-way (free).
// (2) flash K/V double-buffered with ONE barrier per round: DMA for kt+1
// issued at top of round kt, drained by the NEXT round's barrier (full round
// in flight, unlike m97's issue->drain shape). LDS 59.8KB.

typedef unsigned short u16;
typedef __attribute__((ext_vector_type(8))) __bf16 bf16x8;
typedef __attribute__((ext_vector_type(4))) float f32x4;
typedef __attribute__((address_space(1))) const unsigned int gu32;
typedef __attribute__((address_space(3))) unsigned int lu32;

#define LOG2E 1.4426950408889634f

__device__ __forceinline__ float b2f(u16 u) {
    unsigned int i = ((unsigned int)u) << 16;
    float f; __builtin_memcpy(&f, &i, 4); return f;
}
__device__ __forceinline__ u16 f2b(float f) {
    unsigned int x; __builtin_memcpy(&x, &f, 4);
    x += 0x7fffu + ((x >> 16) & 1u);   // RTNE
    return (u16)(x >> 16);
}

#define LDT 72

// ---------------------------------------------------------------------------
__global__ void detect_dtype(const u16* __restrict__ x, int* __restrict__ flag)
{
    if (threadIdx.x == 0 && blockIdx.x == 0) {
        float mx = 0.f;
        for (int i = 0; i < 128; i++) {
            float v = fabsf(b2f(x[i]));
            if (!(v <= 1e30f)) v = 1e30f;
            mx = fmaxf(mx, v);
        }
        *flag = (mx > 1e4f) ? 1 : 0;
    }
}

struct CvtArgs {
    const void* src[7];
    u16*        dst[7];
    int         n[7];
    float       sc[7];
};

__global__ __launch_bounds__(256) void convert_all(CvtArgs a, const int* __restrict__ flag)
{
    const int fl = *flag;
    const int g = blockIdx.x * 256 + threadIdx.x;
    const int stride = gridDim.x * 256;
    #pragma unroll 1
    for (int s = 0; s < 7; s++) {
        const int n = a.n[s];
        const float sc = a.sc[s];
        const float* fs = (const float*)a.src[s];
        const u16*  hs = (const u16*)a.src[s];
        u16* d = a.dst[s];
        for (int i = g; i < n; i += stride) {
            float v = fl ? fs[i] : b2f(hs[i]);
            d[i] = f2b(v * sc);
        }
    }
}

// ---------------------------------------------------------------------------
// 128x128 GEMM (TN), BK=64, swizzled global_load_lds staging.
// EPI=0: proj (dual-dtype store). EPI=1: qkv (rope/scale; LDS-staged stores;
// V -> [bn][kt][d][l64] tile-contiguous).
// ---------------------------------------------------------------------------
template <int EPI>
__global__ __launch_bounds__(256) void gemm128(
    const u16* __restrict__ A, const u16* __restrict__ Bw,
    const u16* __restrict__ bias, void* __restrict__ Cout,
    const int* __restrict__ flag, u16* __restrict__ qkvT, int N, int K)
{
    __shared__ __align__(16) u16 smem[16384];    // lA|lB; reused as ct[128][128]
    u16* lA = smem;
    u16* lB = smem + 8192;
    u16* ct = smem;
    const int tid = threadIdx.x;
    const int m0 = blockIdx.x * 128, n0 = blockIdx.y * 128;
    const int wave = tid >> 6, lane = tid & 63;
    const int wm = (wave & 1) * 64, wn = (wave >> 1) * 64;
    const int lm = lane & 15, lq = lane >> 4;
    const int srow = lane >> 3;
    const int sgcol = ((lane & 7) ^ (srow & 7)) * 8;       // swizzled global col
    const int sw0 = (lq ^ (lm & 7)) * 8;                   // frag col, group lq
    const int sw1 = ((lq + 4) ^ (lm & 7)) * 8;             // frag col, group lq+4
    f32x4 acc[4][4] = {};
    for (int k0 = 0; k0 < K; k0 += 64) {
        if (k0) __syncthreads();
        #pragma unroll
        for (int c4 = 0; c4 < 4; c4++) {
            const int c = wave * 4 + c4;
            const int row = c * 8 + srow;
            __builtin_amdgcn_global_load_lds(
                (gu32*)(A + (size_t)(m0 + row) * K + k0 + sgcol),
                (lu32*)&lA[c * 512], 16, 0, 0);
            __builtin_amdgcn_global_load_lds(
                (gu32*)(Bw + (size_t)(n0 + row) * K + k0 + sgcol),
                (lu32*)&lB[c * 512], 16, 0, 0);
        }
        __syncthreads();
        #pragma unroll
        for (int ks = 0; ks < 64; ks += 32) {
            const int sw = ks ? sw1 : sw0;
            bf16x8 af[4], bfr[4];
            #pragma unroll
            for (int i = 0; i < 4; i++) af[i]  = *(const bf16x8*)&lA[(wm + i * 16 + lm) * 64 + sw];
            #pragma unroll
            for (int j = 0; j < 4; j++) bfr[j] = *(const bf16x8*)&lB[(wn + j * 16 + lm) * 64 + sw];
            #pragma unroll
            for (int i = 0; i < 4; i++)
                #pragma unroll
                for (int j = 0; j < 4; j++)
                    acc[i][j] = __builtin_amdgcn_mfma_f32_16x16x32_bf16(af[i], bfr[j], acc[i][j], 0, 0, 0);
        }
    }
    if (EPI == 0) {
        const int fl = *flag;
        #pragma unroll
        for (int j = 0; j < 4; j++) {
            const int n = n0 + wn + j * 16 + lm;
            const float bj = b2f(bias[n]);
            #pragma unroll
            for (int i = 0; i < 4; i++)
                #pragma unroll
                for (int r = 0; r < 4; r++) {
                    const int m = m0 + wm + i * 16 + lq * 4 + r;
                    const float v = acc[i][j][r] + bj;
                    if (fl) ((float*)Cout)[(size_t)m * 768 + n] = v;
                    else    ((u16*)Cout)[(size_t)m * 768 + n] = f2b(v);
                }
        }
    } else {
        const int which = n0 / 768;
        const bool vt = (which == 2);
        __syncthreads();
        #pragma unroll
        for (int j = 0; j < 4; j++) {
            const int nl = wn + j * 16 + lm;
            const int n = n0 + nl;
            const float bj = b2f(bias[n]);
            #pragma unroll
            for (int i = 0; i < 4; i++)
                #pragma unroll
                for (int r = 0; r < 4; r++) {
                    const int ml = wm + i * 16 + lq * 4 + r;
                    const int m = m0 + ml;
                    float v = acc[i][j][r] + bj;
                    const float p = __shfl_xor(v, 1);
                    const int l = m & 1023, d = n & 63;
                    float o = v;
                    if (which < 2) {
                        const int pi = d >> 1, jj = pi & 15;
                        const float coord = (pi < 16) ? (float)(l & 31) : (float)(l >> 5);
                        const float ang = coord * __expf(-(float)jj * 0.5756462732485115f);
                        float sn, cs; __sincosf(ang, &sn, &cs);
                        o = v * cs + ((d & 1) ? p * sn : -(p * sn));
                        if (which == 1) o *= 0.125f * LOG2E;
                    }
                    ct[vt ? nl * 128 + ml : ml * 128 + nl] = f2b(o);
                }
        }
        __syncthreads();
        const size_t HL = (size_t)96 * 1024 * 64;
        const int nh0 = (n0 >> 6) % 12, bb = m0 >> 10, l0 = m0 & 1023;
        if (!vt) {
            #pragma unroll
            for (int pass = 0; pass < 8; pass++) {
                const int chunk = pass * 256 + tid;
                const int run = chunk >> 3, lc = chunk & 7;
                const int ml = run >> 1, h = run & 1;
                u16* gp = qkvT + (size_t)which * HL
                        + ((size_t)(bb * 12 + nh0 + h) * 1024 + l0 + ml) * 64 + lc * 8;
                *(uint4*)gp = *(const uint4*)&ct[ml * 128 + h * 64 + lc * 8];
            }
        } else {
            const int kt0 = l0 >> 6;
            #pragma unroll
            for (int pass = 0; pass < 8; pass++) {
                const int run = pass * 16 + (tid >> 4);
                const int ln = tid & 15;
                const int half = ln >> 3, l8 = ln & 7;
                u16* gp = qkvT + 2 * HL
                        + (size_t)(bb * 12 + nh0 + (run >> 6)) * 65536
                        + (size_t)(kt0 + half) * 4096 + (run & 63) * 64 + l8 * 8;
                *(uint4*)gp = *(const uint4*)&ct[run * 128 + ln * 8];
            }
        }
    }
}

// ---------------------------------------------------------------------------
// K2: MFMA flash attention. Swizzled DMA staging + double-buffered K/V with
// one barrier per round (DMA for kt+1 in flight during round kt's compute).
// ---------------------------------------------------------------------------
__global__ __launch_bounds__(256) void flash_attn_mfma(
    const u16* __restrict__ qkvT, const u16* __restrict__ relH,
    const u16* __restrict__ relW, u16* __restrict__ outb)
{
    __shared__ __align__(16) u16 ks2[2 * 4096];    // [buf][64][64] swizzled
    __shared__ __align__(16) u16 vsT[2 * 4096];    // [buf][64][64] swizzled
    __shared__ __align__(16) u16 qs[64 * LDT];     // Q tile; aliased as pT
    __shared__ __align__(16) u16 Th[64 * LDT];
    __shared__ __align__(16) u16 Tw[64 * LDT];
    u16* rel = vsT;                                // prologue staging (buf0, unswizzled)
    u16* pT  = qs;

    const int tid = threadIdx.x;
    const int bn = blockIdx.x, q0 = blockIdx.y * 64;
    const size_t HL = (size_t)96 * 1024 * 64;
    const u16* qg  = qkvT + (size_t)bn * 65536 + (size_t)q0 * 64;
    const u16* kgb = qkvT + HL + (size_t)bn * 65536;
    const u16* vgb = qkvT + 2 * HL + (size_t)bn * 65536;   // [kt][d][l64]

    for (int g = tid; g < 1024; g += 256) {
        int r = g >> 4, c = (g & 15) * 4;
        *(ushort4*)&qs[r * LDT + c] = ((const ushort4*)qg)[g];
    }
    for (int g = tid; g < 1008; g += 256) {
        int r = g >> 4, c = (g & 15) * 4;
        *(ushort4*)&rel[r * 64 + c] = *(const ushort4*)(relH + g * 4);
    }
    if (tid < 16) { ushort4 z = {0, 0, 0, 0}; *(ushort4*)&rel[63 * 64 + tid * 4] = z; }
    __syncthreads();

    const int w = tid >> 6, lane = tid & 63;
    const int lm = lane & 15, lq = lane >> 4;

    const bf16x8 bq0 = *(const bf16x8*)&qs[(w * 16 + lm) * LDT + lq * 8];
    const bf16x8 bq1 = *(const bf16x8*)&qs[(w * 16 + lm) * LDT + 32 + lq * 8];

    {   // Th = Q . relH^T   (rel unswizzled; prologue-only conflicts are negligible)
        f32x4 tacc[4] = {};
        #pragma unroll
        for (int nb = 0; nb < 4; nb++) {
            bf16x8 r0 = *(const bf16x8*)&rel[(nb * 16 + lm) * 64 + lq * 8];
            bf16x8 r1 = *(const bf16x8*)&rel[(nb * 16 + lm) * 64 + 32 + lq * 8];
            tacc[nb] = __builtin_amdgcn_mfma_f32_16x16x32_bf16(bq0, r0, tacc[nb], 0, 0, 0);
            tacc[nb] = __builtin_amdgcn_mfma_f32_16x16x32_bf16(bq1, r1, tacc[nb], 0, 0, 0);
        }
        #pragma unroll
        for (int nb = 0; nb < 4; nb++)
            #pragma unroll
            for (int rr = 0; rr < 4; rr++)
                Th[(w * 16 + lq * 4 + rr) * LDT + nb * 16 + lm] = f2b(tacc[nb][rr]);
    }
    __syncthreads();
    for (int g = tid; g < 1008; g += 256) {
        int r = g >> 4, c = (g & 15) * 4;
        *(ushort4*)&rel[r * 64 + c] = *(const ushort4*)(relW + g * 4);
    }
    if (tid < 16) { ushort4 z = {0, 0, 0, 0}; *(ushort4*)&rel[63 * 64 + tid * 4] = z; }
    __syncthreads();
    {   // Tw = Q . relW^T
        f32x4 tacc[4] = {};
        #pragma unroll
        for (int nb = 0; nb < 4; nb++) {
            bf16x8 r0 = *(const bf16x8*)&rel[(nb * 16 + lm) * 64 + lq * 8];
            bf16x8 r1 = *(const bf16x8*)&rel[(nb * 16 + lm) * 64 + 32 + lq * 8];
            tacc[nb] = __builtin_amdgcn_mfma_f32_16x16x32_bf16(bq0, r0, tacc[nb], 0, 0, 0);
            tacc[nb] = __builtin_amdgcn_mfma_f32_16x16x32_bf16(bq1, r1, tacc[nb], 0, 0, 0);
        }
        #pragma unroll
        for (int nb = 0; nb < 4; nb++)
            #pragma unroll
            for (int rr = 0; rr < 4; rr++)
                Tw[(w * 16 + lq * 4 + rr) * LDT + nb * 16 + lm] = f2b(tacc[nb][rr]);
    }
    const int qw = (w & 1) * 16 + lm;
    float rwc[8];
    #pragma unroll
    for (int mb2 = 0; mb2 < 2; mb2++)
        #pragma unroll
        for (int rr = 0; rr < 4; rr++) {
            const int kw = mb2 * 16 + lq * 4 + rr;
            rwc[mb2 * 4 + rr] = b2f(Tw[(w * 16 + lm) * LDT + qw - kw + 31]) - 16.0f;
        }
    const int qh = (q0 >> 5) + (w >= 2 ? 1 : 0);

    const int srow = lane >> 3;
    const int sgcol = ((lane & 7) ^ (srow & 7)) * 8;       // swizzled global col
    const int sw0 = (lq ^ (lm & 7)) * 8;
    const int sw1 = ((lq + 4) ^ (lm & 7)) * 8;
    float l_acc = 0.f;
    f32x4 oacc[4] = {};

    __syncthreads();              // all rel readers done; vsT buf0 reusable
    // prime tile 0 into buf 0
    #pragma unroll
    for (int c4 = 0; c4 < 2; c4++) {
        const int c = w * 2 + c4;
        const int row = c * 8 + srow;
        __builtin_amdgcn_global_load_lds(
            (gu32*)(kgb + row * 64 + sgcol), (lu32*)&ks2[c * 512], 16, 0, 0);
        __builtin_amdgcn_global_load_lds(
            (gu32*)(vgb + row * 64 + sgcol), (lu32*)&vsT[c * 512], 16, 0, 0);
    }

    #pragma unroll 1
    for (int kt = 0; kt < 16; kt++) {
        __syncthreads();           // buf[kt&1] DMA complete; its prior readers done
        const int bo = (kt & 1) * 4096;
        if (kt < 15) {             // issue DMA for kt+1 into the other buffer
            const int bn1 = ((kt + 1) & 1) * 4096;
            const u16* kp = kgb + (size_t)(kt + 1) * 4096;
            const u16* vp = vgb + (size_t)(kt + 1) * 4096;
            #pragma unroll
            for (int c4 = 0; c4 < 2; c4++) {
                const int c = w * 2 + c4;
                const int row = c * 8 + srow;
                __builtin_amdgcn_global_load_lds(
                    (gu32*)(kp + row * 64 + sgcol), (lu32*)&ks2[bn1 + c * 512], 16, 0, 0);
                __builtin_amdgcn_global_load_lds(
                    (gu32*)(vp + row * 64 + sgcol), (lu32*)&vsT[bn1 + c * 512], 16, 0, 0);
            }
        }
        f32x4 sacc[4];
        #pragma unroll
        for (int mb = 0; mb < 4; mb++) {
            bf16x8 ka0 = *(const bf16x8*)&ks2[bo + (mb * 16 + lm) * 64 + sw0];
            bf16x8 ka1 = *(const bf16x8*)&ks2[bo + (mb * 16 + lm) * 64 + sw1];
            f32x4 s = {};
            s = __builtin_amdgcn_mfma_f32_16x16x32_bf16(ka0, bq0, s, 0, 0, 0);
            s = __builtin_amdgcn_mfma_f32_16x16x32_bf16(ka1, bq1, s, 0, 0, 0);
            sacc[mb] = s;
        }
        const float rh0 = b2f(Th[(w * 16 + lm) * LDT + qh - 2 * kt + 31]);
        const float rh1 = b2f(Th[(w * 16 + lm) * LDT + qh - 2 * kt + 30]);
        #pragma unroll
        for (int mb = 0; mb < 4; mb++) {
            const float rhv = (mb >= 2) ? rh1 : rh0;
            unsigned pk[2];
            #pragma unroll
            for (int h = 0; h < 2; h++) {
                float p0 = exp2f(sacc[mb][2 * h]     + rhv + rwc[(mb & 1) * 4 + 2 * h]);
                float p1 = exp2f(sacc[mb][2 * h + 1] + rhv + rwc[(mb & 1) * 4 + 2 * h + 1]);
                l_acc += p0; l_acc += p1;
                unsigned u0, u1;
                __builtin_memcpy(&u0, &p0, 4); __builtin_memcpy(&u1, &p1, 4);
                pk[h] = __builtin_amdgcn_perm(u1 + 0x8000u, u0 + 0x8000u, 0x07060302u);
            }
            uint2 u = {pk[0], pk[1]};
            *(uint2*)&pT[(w * 16 + lm) * LDT + mb * 16 + lq * 4] = u;   // wave-private
        }
        const bf16x8 pa0 = *(const bf16x8*)&pT[(w * 16 + lm) * LDT + lq * 8];
        const bf16x8 pa1 = *(const bf16x8*)&pT[(w * 16 + lm) * LDT + 32 + lq * 8];
        #pragma unroll
        for (int nb = 0; nb < 4; nb++) {
            bf16x8 vb0 = *(const bf16x8*)&vsT[bo + (nb * 16 + lm) * 64 + sw0];
            bf16x8 vb1 = *(const bf16x8*)&vsT[bo + (nb * 16 + lm) * 64 + sw1];
            oacc[nb] = __builtin_amdgcn_mfma_f32_16x16x32_bf16(pa0, vb0, oacc[nb], 0, 0, 0);
            oacc[nb] = __builtin_amdgcn_mfma_f32_16x16x32_bf16(pa1, vb1, oacc[nb], 0, 0, 0);
        }
    }
    l_acc += __shfl_xor(l_acc, 16);
    l_acc += __shfl_xor(l_acc, 32);
    const float rinv = 1.f / l_acc;
    float rv[4];
    #pragma unroll
    for (int rr = 0; rr < 4; rr++) rv[rr] = __shfl(rinv, lq * 4 + rr);
    const int bb = bn / 12, nh = bn % 12;
    #pragma unroll
    for (int nb = 0; nb < 4; nb++)
        #pragma unroll
        for (int rr = 0; rr < 4; rr++) {
            const int qrow = q0 + w * 16 + lq * 4 + rr;
            const int d = nb * 16 + lm;
            outb[((size_t)(bb * 1024 + qrow)) * 768 + nh * 64 + d] = f2b(oacc[nb][rr] * rv[rr]);
        }
}

// ---------------------------------------------------------------------------
extern "C" void kernel_launch(void* const* d_in, const int* in_sizes, int n_in,
                              void* d_out, int out_size, void* d_ws, size_t ws_size,
                              hipStream_t stream)
{
    u16* ws16  = (u16*)d_ws;
    u16* qkvT  = ws16;
    u16* xb    = ws16 + (size_t)18874368;
    u16* attn  = xb;                       // x dead after K1
    const size_t S = 25165824;
    u16* qkvw_b = ws16 + S;
    u16* projw_b = qkvw_b + 1769472;
    u16* qkvb_b = projw_b + 589824;
    u16* projb_b = qkvb_b + 2304;
    u16* relh_b = projb_b + 768;
    u16* relw_b = relh_b + 4032;
    int* flag = (int*)(ws16 + S + 2370432);

    detect_dtype<<<1, 64, 0, stream>>>((const u16*)d_in[0], flag);

    CvtArgs ca;
    ca.src[0] = d_in[0]; ca.dst[0] = xb;      ca.n[0] = 6291456; ca.sc[0] = 1.0f;
    ca.src[1] = d_in[1]; ca.dst[1] = qkvw_b;  ca.n[1] = 1769472; ca.sc[1] = 1.0f;
    ca.src[2] = d_in[3]; ca.dst[2] = projw_b; ca.n[2] = 589824;  ca.sc[2] = 1.0f;
    ca.src[3] = d_in[2]; ca.dst[3] = qkvb_b;  ca.n[3] = 2304;    ca.sc[3] = 1.0f;
    ca.src[4] = d_in[4]; ca.dst[4] = projb_b; ca.n[4] = 768;     ca.sc[4] = 1.0f;
    ca.src[5] = d_in[5]; ca.dst[5] = relh_b;  ca.n[5] = 4032;    ca.sc[5] = LOG2E;
    ca.src[6] = d_in[6]; ca.dst[6] = relw_b;  ca.n[6] = 4032;    ca.sc[6] = LOG2E;
    convert_all<<<2048, 256, 0, stream>>>(ca, flag);

    gemm128<1><<<dim3(64, 18), 256, 0, stream>>>(xb, qkvw_b, qkvb_b, nullptr, flag, qkvT, 2304, 768);
    flash_attn_mfma<<<dim3(96, 16), 256, 0, stream>>>(qkvT, relh_b, relw_b, attn);
    gemm128<0><<<dim3(64, 6), 256, 0, stream>>>(attn, projw_b, projb_b, d_out, flag, nullptr, 768, 768);
}